// Round 1
// baseline (195.456 us; speedup 1.0000x reference)
//
#include <hip/hip_runtime.h>
#include <math.h>

#define NS   16383      // T-1 steps
#define TPB  256
#define LPB  64         // timesteps per block (= lanes of a wave)
#define NBLK 256        // ceil(NS/LPB)
#define STR  65         // LDS row stride in floats (bank-conflict-free pad)

__device__ __forceinline__ float lrelu(float x) { return x >= 0.f ? x : 0.01f * x; }

// one dense layer: 100 outputs split 25/wave, input K dims from LDS [k*STR+lane]
#define DENSE100(INLDS, K, Wp, bp, OUTLDS)                                 \
    {                                                                      \
        const int n0 = w * 25;                                             \
        float acc[25];                                                     \
        _Pragma("unroll")                                                  \
        for (int j = 0; j < 25; ++j) acc[j] = bp[n0 + j];                  \
        _Pragma("unroll 4")                                                \
        for (int k = 0; k < (K); ++k) {                                    \
            const float r = INLDS[k * STR + lane];                         \
            _Pragma("unroll")                                              \
            for (int j = 0; j < 25; ++j)                                   \
                acc[j] = fmaf(r, Wp[(n0 + j) * (K) + k], acc[j]);          \
        }                                                                  \
        _Pragma("unroll")                                                  \
        for (int j = 0; j < 25; ++j)                                       \
            OUTLDS[(n0 + j) * STR + lane] = lrelu(acc[j]);                 \
    }

__global__ __launch_bounds__(TPB, 2)
void k1_encode(const float* __restrict__ z_seq, const float* __restrict__ a_seq,
               const float* __restrict__ W1, const float* __restrict__ b1,
               const float* __restrict__ W2, const float* __restrict__ b2,
               const float* __restrict__ W3, const float* __restrict__ b3,
               const float* __restrict__ W4, const float* __restrict__ b4,
               float* __restrict__ g_inter, float* __restrict__ g_delta,
               float* __restrict__ g_csum)
{
    __shared__ float A[102 * STR];   // az, later u3
    __shared__ float B[100 * STR];   // v1, later delta
    __shared__ float C[100 * STR];   // inter

    const int tid  = threadIdx.x;
    const int lane = tid & 63;
    const int w    = __builtin_amdgcn_readfirstlane(tid >> 6);
    const int t0   = blockIdx.x * LPB;

    // stage az: A[k][lane], k=0..1 from a, k=2..101 from z (coalesced global reads)
    for (int idx = tid; idx < LPB * 100; idx += TPB) {
        const int l = idx / 100, j = idx - l * 100;
        const int t = t0 + l;
        A[(2 + j) * STR + l] = (t < NS) ? z_seq[t * 100 + j] : 0.f;
    }
    if (tid < LPB * 2) {
        const int l = tid >> 1, j = tid & 1;
        const int t = t0 + l;
        A[j * STR + l] = (t < NS) ? a_seq[t * 2 + j] : 0.f;
    }
    __syncthreads();

    DENSE100(A, 102, W1, b1, B);   // L1: az -> v1
    __syncthreads();
    DENSE100(B, 100, W2, b2, C);   // L2: v1 -> inter
    __syncthreads();
    DENSE100(C, 100, W3, b3, A);   // L3: inter -> u
    __syncthreads();

    // L4: delta = W4 @ u + b4 (no activation), 50 outputs -> B rows 0..49
    {
        const int n0 = w * 13;
        const bool vl = (t0 + lane) < NS;
        float acc[13];
        #pragma unroll
        for (int j = 0; j < 13; ++j) {
            int n = n0 + j; n = n < 50 ? n : 49;
            acc[j] = b4[n];
        }
        #pragma unroll 4
        for (int k = 0; k < 100; ++k) {
            const float r = A[k * STR + lane];
            #pragma unroll
            for (int j = 0; j < 13; ++j) {
                int n = n0 + j; n = n < 50 ? n : 49;   // clamp: avoid OOB W4 read
                acc[j] = fmaf(r, W4[n * 100 + k], acc[j]);
            }
        }
        #pragma unroll
        for (int j = 0; j < 13; ++j) {
            const int n = n0 + j;
            if (n < 50) B[n * STR + lane] = vl ? acc[j] : 0.f;
        }
    }
    __syncthreads();

    // store inter [NS,100] and delta [NS,50] (coalesced), chunk-sum delta
    for (int idx = tid; idx < LPB * 100; idx += TPB) {
        const int l = idx / 100, j = idx - l * 100;
        const int t = t0 + l;
        if (t < NS) g_inter[t * 100 + j] = C[j * STR + l];
    }
    for (int idx = tid; idx < LPB * 50; idx += TPB) {
        const int l = idx / 50, j = idx - l * 50;
        const int t = t0 + l;
        if (t < NS) g_delta[t * 50 + j] = B[j * STR + l];
    }
    if (tid < 50) {
        float s = 0.f;
        for (int l = 0; l < LPB; ++l) s += B[tid * STR + l];
        g_csum[blockIdx.x * 50 + tid] = s;
    }
}

__global__ void k2_scan(const float* __restrict__ g_csum, float* __restrict__ g_coff)
{
    const int n = threadIdx.x;
    if (n < 50) {
        float run = 0.f;
        for (int c = 0; c < NBLK; ++c) {
            g_coff[c * 50 + n] = run;
            run += g_csum[c * 50 + n];
        }
    }
}

__global__ __launch_bounds__(TPB, 2)
void k3_predict(const float* __restrict__ z_seq, const float* __restrict__ term_seq,
                const float* __restrict__ g_inter, const float* __restrict__ g_delta,
                const float* __restrict__ g_coff,
                const float* __restrict__ W5, const float* __restrict__ b5,
                const float* __restrict__ Wz, const float* __restrict__ bz,
                const float* __restrict__ Wt, const float* __restrict__ bt,
                float* __restrict__ g_bz, float* __restrict__ g_bt)
{
    __shared__ float X[100 * STR];   // inter
    __shared__ float Y[100 * STR];   // i5
    __shared__ float Zb[100 * STR];  // delta -> h -> z_next
    __shared__ float red[4];

    const int tid  = threadIdx.x;
    const int lane = tid & 63;
    const int w    = __builtin_amdgcn_readfirstlane(tid >> 6);
    const int blk  = blockIdx.x;
    const int t0   = blk * LPB;
    const bool vl  = (t0 + lane) < NS;

    for (int idx = tid; idx < LPB * 100; idx += TPB) {
        const int l = idx / 100, j = idx - l * 100;
        const int t = t0 + l;
        X[j * STR + l] = (t < NS) ? g_inter[t * 100 + j] : 0.f;
    }
    for (int idx = tid; idx < LPB * 50; idx += TPB) {
        const int l = idx / 50, j = idx - l * 50;
        const int t = t0 + l;
        Zb[j * STR + l] = (t < NS) ? g_delta[t * 50 + j] : 0.f;
    }
    __syncthreads();

    // inclusive scan over the 64 lanes per h-dim + chunk offset -> h_t
    for (int n = w; n < 50; n += 4) {
        float v = Zb[n * STR + lane];
        #pragma unroll
        for (int off = 1; off < 64; off <<= 1) {
            const float u = __shfl_up(v, off, 64);
            if (lane >= off) v += u;
        }
        Zb[n * STR + lane] = v + g_coff[blk * 50 + n];
    }
    __syncthreads();

    // L5: i5 = lrelu(W5 @ [h(50); inter(100)] + b5) -> Y
    {
        const int n0 = w * 25;
        float acc[25];
        #pragma unroll
        for (int j = 0; j < 25; ++j) acc[j] = b5[n0 + j];
        #pragma unroll 4
        for (int k = 0; k < 50; ++k) {
            const float r = Zb[k * STR + lane];
            #pragma unroll
            for (int j = 0; j < 25; ++j)
                acc[j] = fmaf(r, W5[(n0 + j) * 150 + k], acc[j]);
        }
        #pragma unroll 4
        for (int k = 0; k < 100; ++k) {
            const float r = X[k * STR + lane];
            #pragma unroll
            for (int j = 0; j < 25; ++j)
                acc[j] = fmaf(r, W5[(n0 + j) * 150 + 50 + k], acc[j]);
        }
        #pragma unroll
        for (int j = 0; j < 25; ++j) Y[(n0 + j) * STR + lane] = lrelu(acc[j]);
    }
    __syncthreads();

    // overwrite Zb with z_next
    for (int idx = tid; idx < LPB * 100; idx += TPB) {
        const int l = idx / 100, j = idx - l * 100;
        const int t = t0 + l;
        Zb[j * STR + l] = (t < NS) ? z_seq[(t + 1) * 100 + j] : 0.f;
    }
    __syncthreads();

    // z_pred = Wz @ i5 + bz ; accumulate squared error
    float zpart = 0.f;
    {
        const int n0 = w * 25;
        float acc[25];
        #pragma unroll
        for (int j = 0; j < 25; ++j) acc[j] = bz[n0 + j];
        #pragma unroll 4
        for (int k = 0; k < 100; ++k) {
            const float r = Y[k * STR + lane];
            #pragma unroll
            for (int j = 0; j < 25; ++j)
                acc[j] = fmaf(r, Wz[(n0 + j) * 100 + k], acc[j]);
        }
        #pragma unroll
        for (int j = 0; j < 25; ++j) {
            const float d = Zb[(n0 + j) * STR + lane] - acc[j];
            zpart += d * d;
        }
        if (!vl) zpart = 0.f;
    }

    // t_logit + BCE (wave 0 only; lane == timestep)
    float tpart = 0.f;
    if (w == 0) {
        float acc = bt[0];
        #pragma unroll 4
        for (int k = 0; k < 100; ++k)
            acc = fmaf(Y[k * STR + lane], Wt[k], acc);
        if (vl) {
            const float y = term_seq[t0 + lane + 1];
            tpart = fmaxf(acc, 0.f) - acc * y + log1pf(expf(-fabsf(acc)));
        }
    }

    #pragma unroll
    for (int off = 32; off > 0; off >>= 1) zpart += __shfl_xor(zpart, off, 64);
    if (lane == 0) red[w] = zpart;
    __syncthreads();
    if (tid == 0) g_bz[blk] = red[0] + red[1] + red[2] + red[3];
    if (w == 0) {
        #pragma unroll
        for (int off = 32; off > 0; off >>= 1) tpart += __shfl_xor(tpart, off, 64);
        if (lane == 0) g_bt[blk] = tpart;
    }
}

__global__ void k4_final(const float* __restrict__ g_bz, const float* __restrict__ g_bt,
                         float* __restrict__ out)
{
    __shared__ float rz[4], rt[4];
    const int tid  = threadIdx.x;
    const int lane = tid & 63;
    const int w    = tid >> 6;
    float z = g_bz[tid];
    float t = g_bt[tid];
    #pragma unroll
    for (int off = 32; off > 0; off >>= 1) {
        z += __shfl_xor(z, off, 64);
        t += __shfl_xor(t, off, 64);
    }
    if (lane == 0) { rz[w] = z; rt[w] = t; }
    __syncthreads();
    if (tid == 0) {
        const float sz = rz[0] + rz[1] + rz[2] + rz[3];
        const float st = rt[0] + rt[1] + rt[2] + rt[3];
        const float zl = sz / (100.0f * NS);
        const float tl = st / NS;
        out[0] = zl + tl;
        out[1] = zl;
        out[2] = tl;
    }
}

extern "C" void kernel_launch(void* const* d_in, const int* in_sizes, int n_in,
                              void* d_out, int out_size, void* d_ws, size_t ws_size,
                              hipStream_t stream)
{
    const float* z_seq = (const float*)d_in[0];
    const float* a_seq = (const float*)d_in[1];
    const float* term  = (const float*)d_in[2];
    const float* W1 = (const float*)d_in[3];  const float* b1 = (const float*)d_in[4];
    const float* W2 = (const float*)d_in[5];  const float* b2 = (const float*)d_in[6];
    const float* W3 = (const float*)d_in[7];  const float* b3 = (const float*)d_in[8];
    const float* W4 = (const float*)d_in[9];  const float* b4 = (const float*)d_in[10];
    const float* W5 = (const float*)d_in[11]; const float* b5 = (const float*)d_in[12];
    const float* Wz = (const float*)d_in[13]; const float* bz = (const float*)d_in[14];
    const float* Wt = (const float*)d_in[15]; const float* bt = (const float*)d_in[16];
    float* out = (float*)d_out;

    float* ws = (float*)d_ws;
    float* g_inter = ws;                               // NS*100
    float* g_delta = g_inter + (size_t)NS * 100;       // NS*50
    float* g_csum  = g_delta + (size_t)NS * 50;        // NBLK*50
    float* g_coff  = g_csum + (size_t)NBLK * 50;       // NBLK*50
    float* g_bz    = g_coff + (size_t)NBLK * 50;       // NBLK
    float* g_bt    = g_bz + NBLK;                      // NBLK

    k1_encode<<<NBLK, TPB, 0, stream>>>(z_seq, a_seq, W1, b1, W2, b2, W3, b3, W4, b4,
                                        g_inter, g_delta, g_csum);
    k2_scan<<<1, 64, 0, stream>>>(g_csum, g_coff);
    k3_predict<<<NBLK, TPB, 0, stream>>>(z_seq, term, g_inter, g_delta, g_coff,
                                         W5, b5, Wz, bz, Wt, bt, g_bz, g_bt);
    k4_final<<<1, TPB, 0, stream>>>(g_bz, g_bt, out);
}

// Round 2
// 146.068 us; speedup vs baseline: 1.3381x; 1.3381x over previous
//
#include <hip/hip_runtime.h>
#include <math.h>

#define NS   16383      // T-1 steps
#define NSP  16384      // padded stride for [dim][t] arrays
#define TPB  256
#define LPB  64         // timesteps per block (= lanes of a wave)
#define NBLK 256        // NS / LPB (ceil)
#define STR  65         // LDS row stride in floats

// ---- ws layout (floats) ----
#define OFF_ZT     0                        // 100*NSP
#define OFF_AT     (OFF_ZT + 100*NSP)       // 2*NSP
#define OFF_INTERT (OFF_AT + 2*NSP)         // 100*NSP
#define OFF_DELTAT (OFF_INTERT + 100*NSP)   // 50*NSP
#define OFF_W1T    (OFF_DELTAT + 50*NSP)    // 102*112
#define OFF_W2T    (OFF_W1T + 102*112)      // 100*112
#define OFF_W3T    (OFF_W2T + 100*112)      // 100*112
#define OFF_W4T    (OFF_W3T + 100*112)      // 100*64
#define OFF_W5T    (OFF_W4T + 100*64)       // 150*112
#define OFF_WZT    (OFF_W5T + 150*112)      // 100*112
#define OFF_CSUM   (OFF_WZT + 100*112)      // 50*NBLK
#define OFF_COFF   (OFF_CSUM + 50*NBLK)     // 50*NBLK
#define OFF_BZ     (OFF_COFF + 50*NBLK)     // NBLK
#define OFF_BT     (OFF_BZ + NBLK)          // NBLK

__device__ __forceinline__ float lrelu(float x) { return x >= 0.f ? x : 0.01f * x; }

// dense layer: 25 outputs per wave, weights padded [K][4][28] as float4 (7/wave/k)
#define DENSE25(INLDS, KDIM, WT4, BIAS, acc)                                \
    {                                                                       \
        _Pragma("unroll")                                                   \
        for (int j = 0; j < 25; ++j) acc[j] = BIAS[n0 + j];                 \
        _Pragma("unroll 2")                                                 \
        for (int k = 0; k < (KDIM); ++k) {                                  \
            const float r = INLDS[k * STR + lane];                          \
            const float4* Wk = (WT4) + k * 28 + w * 7;                      \
            _Pragma("unroll")                                               \
            for (int q = 0; q < 7; ++q) {                                   \
                const float4 wv = Wk[q];                                    \
                acc[4*q+0] = fmaf(r, wv.x, acc[4*q+0]);                     \
                if (4*q+1 < 25) acc[4*q+1] = fmaf(r, wv.y, acc[4*q+1]);     \
                if (4*q+2 < 25) acc[4*q+2] = fmaf(r, wv.z, acc[4*q+2]);     \
                if (4*q+3 < 25) acc[4*q+3] = fmaf(r, wv.w, acc[4*q+3]);     \
            }                                                               \
        }                                                                   \
    }

// ---------- k0a: transpose z_seq [16384][100] -> zT [100][16384] (tiled) ----------
__global__ __launch_bounds__(TPB)
void k0_ztrans(const float* __restrict__ z_seq, float* __restrict__ zT)
{
    __shared__ float tile[50 * 65];
    const int bx = blockIdx.x;
    const int tt = bx >> 1;          // 0..255 time tile
    const int cc = (bx & 1) * 50;    // column half
    const int tid = threadIdx.x;
    for (int idx = tid; idx < 64 * 50; idx += TPB) {
        const int l = idx / 50, j = idx - l * 50;
        tile[j * 65 + l] = z_seq[(tt * 64 + l) * 100 + cc + j];
    }
    __syncthreads();
    for (int idx = tid; idx < 50 * 64; idx += TPB) {
        const int n = idx >> 6, l = idx & 63;
        zT[(cc + n) * NSP + tt * 64 + l] = tile[n * 65 + l];
    }
}

// ---------- k0b: weight transposes + aT ----------
__global__ __launch_bounds__(TPB)
void k0_prep(const float* __restrict__ a_seq,
             const float* __restrict__ W1, const float* __restrict__ W2,
             const float* __restrict__ W3, const float* __restrict__ W4,
             const float* __restrict__ W5, const float* __restrict__ Wz,
             float* __restrict__ ws)
{
    const int gid = blockIdx.x * TPB + threadIdx.x;
    int idx = gid;
    // w1t [102][4][28]
    if (idx < 102 * 112) {
        const int k = idx / 112, r = idx - k * 112, g = r / 28, j = r - g * 28;
        ws[OFF_W1T + idx] = (j < 25) ? W1[(g * 25 + j) * 102 + k] : 0.f;
        return;
    }
    idx -= 102 * 112;
    if (idx < 100 * 112) {
        const int k = idx / 112, r = idx - k * 112, g = r / 28, j = r - g * 28;
        ws[OFF_W2T + idx] = (j < 25) ? W2[(g * 25 + j) * 100 + k] : 0.f;
        return;
    }
    idx -= 100 * 112;
    if (idx < 100 * 112) {
        const int k = idx / 112, r = idx - k * 112, g = r / 28, j = r - g * 28;
        ws[OFF_W3T + idx] = (j < 25) ? W3[(g * 25 + j) * 100 + k] : 0.f;
        return;
    }
    idx -= 100 * 112;
    // w4t [100][4][16]
    if (idx < 100 * 64) {
        const int k = idx / 64, r = idx - k * 64, g = r / 16, j = r - g * 16;
        const int n = g * 13 + j;
        ws[OFF_W4T + idx] = (j < 13 && n < 50) ? W4[n * 100 + k] : 0.f;
        return;
    }
    idx -= 100 * 64;
    if (idx < 150 * 112) {
        const int k = idx / 112, r = idx - k * 112, g = r / 28, j = r - g * 28;
        ws[OFF_W5T + idx] = (j < 25) ? W5[(g * 25 + j) * 150 + k] : 0.f;
        return;
    }
    idx -= 150 * 112;
    if (idx < 100 * 112) {
        const int k = idx / 112, r = idx - k * 112, g = r / 28, j = r - g * 28;
        ws[OFF_WZT + idx] = (j < 25) ? Wz[(g * 25 + j) * 100 + k] : 0.f;
        return;
    }
    idx -= 100 * 112;
    // aT [2][NSP]
    if (idx < 2 * NSP) {
        const int j = idx / NSP, t = idx - j * NSP;
        ws[OFF_AT + idx] = (t < NS) ? a_seq[t * 2 + j] : 0.f;
        return;
    }
}

// ---------- k1: 4-layer encoder, single LDS buffer ----------
__global__ __launch_bounds__(TPB)
void k1_encode(const float* __restrict__ ws_c, float* __restrict__ ws_m,
               const float* __restrict__ b1, const float* __restrict__ b2,
               const float* __restrict__ b3, const float* __restrict__ b4)
{
    __shared__ float A[102 * STR];

    const int tid  = threadIdx.x;
    const int lane = tid & 63;
    const int w    = __builtin_amdgcn_readfirstlane(tid >> 6);
    const int n0   = w * 25;
    const int blk  = blockIdx.x;
    const int t0   = blk * LPB;
    const bool vl  = (t0 + lane) < NS;

    const float*  zT   = ws_c + OFF_ZT;
    const float*  aT   = ws_c + OFF_AT;
    const float4* w1t4 = (const float4*)(ws_c + OFF_W1T);
    const float4* w2t4 = (const float4*)(ws_c + OFF_W2T);
    const float4* w3t4 = (const float4*)(ws_c + OFF_W3T);
    const float4* w4t4 = (const float4*)(ws_c + OFF_W4T);
    float* interT = ws_m + OFF_INTERT;
    float* deltaT = ws_m + OFF_DELTAT;
    float* csum   = ws_m + OFF_CSUM;

    // stage az: rows 0..1 = a, rows 2..101 = z (coalesced from transposed arrays)
    for (int idx = tid; idx < 102 * 64; idx += TPB) {
        const int rr = idx >> 6, l = idx & 63;
        const float v = (rr < 2) ? aT[rr * NSP + t0 + l] : zT[(rr - 2) * NSP + t0 + l];
        A[rr * STR + l] = v;
    }
    __syncthreads();

    float acc[25];
    // L1: az(102) -> v1
    DENSE25(A, 102, w1t4, b1, acc);
    __syncthreads();
    #pragma unroll
    for (int j = 0; j < 25; ++j) A[(n0 + j) * STR + lane] = lrelu(acc[j]);
    __syncthreads();

    // L2: v1 -> inter (store inter to global from regs)
    DENSE25(A, 100, w2t4, b2, acc);
    __syncthreads();
    #pragma unroll
    for (int j = 0; j < 25; ++j) {
        const float v = lrelu(acc[j]);
        A[(n0 + j) * STR + lane] = v;
        if (vl) interT[(n0 + j) * NSP + t0 + lane] = v;
    }
    __syncthreads();

    // L3: inter -> u
    DENSE25(A, 100, w3t4, b3, acc);
    __syncthreads();
    #pragma unroll
    for (int j = 0; j < 25; ++j) A[(n0 + j) * STR + lane] = lrelu(acc[j]);
    __syncthreads();

    // L4: delta = W4 @ u + b4 (13/wave, padded slot 16)
    {
        const int m0 = w * 13;
        float acc4[13];
        #pragma unroll
        for (int j = 0; j < 13; ++j) acc4[j] = (m0 + j < 50) ? b4[m0 + j] : 0.f;
        #pragma unroll 2
        for (int k = 0; k < 100; ++k) {
            const float r = A[k * STR + lane];
            const float4* Wk = w4t4 + k * 16 + w * 4;
            #pragma unroll
            for (int q = 0; q < 4; ++q) {
                const float4 wv = Wk[q];
                acc4[4*q+0] = fmaf(r, wv.x, acc4[4*q+0]);
                if (4*q+1 < 13) acc4[4*q+1] = fmaf(r, wv.y, acc4[4*q+1]);
                if (4*q+2 < 13) acc4[4*q+2] = fmaf(r, wv.z, acc4[4*q+2]);
                if (4*q+3 < 13) acc4[4*q+3] = fmaf(r, wv.w, acc4[4*q+3]);
            }
        }
        #pragma unroll
        for (int j = 0; j < 13; ++j) {
            const int n = m0 + j;
            if (n < 50) {
                const float d = vl ? acc4[j] : 0.f;
                deltaT[n * NSP + t0 + lane] = d;
                float s = d;
                #pragma unroll
                for (int off = 32; off > 0; off >>= 1) s += __shfl_xor(s, off, 64);
                if (lane == 0) csum[n * NBLK + blk] = s;
            }
        }
    }
}

// ---------- k2: parallel chunk-offset scan (50 neurons x 256 chunks) ----------
__global__ __launch_bounds__(TPB)
void k2_scan(const float* __restrict__ ws_c, float* __restrict__ ws_m)
{
    __shared__ float part[64][4];
    const float* csum = ws_c + OFF_CSUM;
    float* coff = ws_m + OFF_COFF;
    const int tid = threadIdx.x;
    const int n = tid >> 2, sub = tid & 3;
    float s = 0.f;
    if (n < 50) {
        #pragma unroll 8
        for (int c = 0; c < 64; ++c) s += csum[n * NBLK + sub * 64 + c];
    }
    part[n][sub] = s;
    __syncthreads();
    if (n < 50) {
        float run = 0.f;
        for (int i = 0; i < sub; ++i) run += part[n][i];
        #pragma unroll 8
        for (int c = 0; c < 64; ++c) {
            const int cc = sub * 64 + c;
            coff[n * NBLK + cc] = run;
            run += csum[n * NBLK + cc];
        }
    }
}

// ---------- k3: h-scan + predict + losses ----------
__global__ __launch_bounds__(TPB)
void k3_predict(const float* __restrict__ ws_c, float* __restrict__ ws_m,
                const float* __restrict__ term_seq,
                const float* __restrict__ b5, const float* __restrict__ bz,
                const float* __restrict__ Wt, const float* __restrict__ bt)
{
    __shared__ float X[100 * STR];   // inter -> i5
    __shared__ float H[50 * STR];    // delta -> h
    __shared__ float red[4];

    const int tid  = threadIdx.x;
    const int lane = tid & 63;
    const int w    = __builtin_amdgcn_readfirstlane(tid >> 6);
    const int n0   = w * 25;
    const int blk  = blockIdx.x;
    const int t0   = blk * LPB;
    const bool vl  = (t0 + lane) < NS;

    const float*  zT     = ws_c + OFF_ZT;
    const float*  interT = ws_c + OFF_INTERT;
    const float*  deltaT = ws_c + OFF_DELTAT;
    const float*  coff   = ws_c + OFF_COFF;
    const float4* w5t4   = (const float4*)(ws_c + OFF_W5T);
    const float4* wzt4   = (const float4*)(ws_c + OFF_WZT);
    float* g_bz = ws_m + OFF_BZ;
    float* g_bt = ws_m + OFF_BT;

    // prefetch z_next into regs (coalesced via zT), issued before everything
    float zn[25];
    {
        const int t1 = min(t0 + lane + 1, NS);
        #pragma unroll
        for (int j = 0; j < 25; ++j) zn[j] = zT[(n0 + j) * NSP + t1];
    }

    for (int idx = tid; idx < 100 * 64; idx += TPB) {
        const int n = idx >> 6, l = idx & 63;
        X[n * STR + l] = (t0 + l < NS) ? interT[n * NSP + t0 + l] : 0.f;
    }
    for (int idx = tid; idx < 50 * 64; idx += TPB) {
        const int n = idx >> 6, l = idx & 63;
        H[n * STR + l] = (t0 + l < NS) ? deltaT[n * NSP + t0 + l] : 0.f;
    }
    __syncthreads();

    // inclusive scan over 64 lanes per h-dim + chunk offset
    for (int n = w; n < 50; n += 4) {
        float v = H[n * STR + lane];
        #pragma unroll
        for (int off = 1; off < 64; off <<= 1) {
            const float u = __shfl_up(v, off, 64);
            if (lane >= off) v += u;
        }
        H[n * STR + lane] = v + coff[n * NBLK + blk];
    }
    __syncthreads();

    // L5: i5 = lrelu(W5 @ [h(50); inter(100)] + b5), into regs
    float acc[25];
    #pragma unroll
    for (int j = 0; j < 25; ++j) acc[j] = b5[n0 + j];
    #pragma unroll 2
    for (int k = 0; k < 50; ++k) {
        const float r = H[k * STR + lane];
        const float4* Wk = w5t4 + k * 28 + w * 7;
        #pragma unroll
        for (int q = 0; q < 7; ++q) {
            const float4 wv = Wk[q];
            acc[4*q+0] = fmaf(r, wv.x, acc[4*q+0]);
            if (4*q+1 < 25) acc[4*q+1] = fmaf(r, wv.y, acc[4*q+1]);
            if (4*q+2 < 25) acc[4*q+2] = fmaf(r, wv.z, acc[4*q+2]);
            if (4*q+3 < 25) acc[4*q+3] = fmaf(r, wv.w, acc[4*q+3]);
        }
    }
    #pragma unroll 2
    for (int k = 0; k < 100; ++k) {
        const float r = X[k * STR + lane];
        const float4* Wk = w5t4 + (50 + k) * 28 + w * 7;
        #pragma unroll
        for (int q = 0; q < 7; ++q) {
            const float4 wv = Wk[q];
            acc[4*q+0] = fmaf(r, wv.x, acc[4*q+0]);
            if (4*q+1 < 25) acc[4*q+1] = fmaf(r, wv.y, acc[4*q+1]);
            if (4*q+2 < 25) acc[4*q+2] = fmaf(r, wv.z, acc[4*q+2]);
            if (4*q+3 < 25) acc[4*q+3] = fmaf(r, wv.w, acc[4*q+3]);
        }
    }
    __syncthreads();
    #pragma unroll
    for (int j = 0; j < 25; ++j) X[(n0 + j) * STR + lane] = lrelu(acc[j]);
    __syncthreads();

    // z_pred = Wz @ i5 + bz; squared error vs zn
    float zpart = 0.f;
    {
        float a2[25];
        #pragma unroll
        for (int j = 0; j < 25; ++j) a2[j] = bz[n0 + j];
        #pragma unroll 2
        for (int k = 0; k < 100; ++k) {
            const float r = X[k * STR + lane];
            const float4* Wk = wzt4 + k * 28 + w * 7;
            #pragma unroll
            for (int q = 0; q < 7; ++q) {
                const float4 wv = Wk[q];
                a2[4*q+0] = fmaf(r, wv.x, a2[4*q+0]);
                if (4*q+1 < 25) a2[4*q+1] = fmaf(r, wv.y, a2[4*q+1]);
                if (4*q+2 < 25) a2[4*q+2] = fmaf(r, wv.z, a2[4*q+2]);
                if (4*q+3 < 25) a2[4*q+3] = fmaf(r, wv.w, a2[4*q+3]);
            }
        }
        #pragma unroll
        for (int j = 0; j < 25; ++j) {
            const float d = zn[j] - a2[j];
            zpart += d * d;
        }
        if (!vl) zpart = 0.f;
    }

    // t_logit + BCE (wave 0)
    float tpart = 0.f;
    if (w == 0) {
        float a = bt[0];
        #pragma unroll 4
        for (int k = 0; k < 100; ++k) a = fmaf(X[k * STR + lane], Wt[k], a);
        if (vl) {
            const float y = term_seq[t0 + lane + 1];
            tpart = fmaxf(a, 0.f) - a * y + log1pf(expf(-fabsf(a)));
        }
    }

    #pragma unroll
    for (int off = 32; off > 0; off >>= 1) zpart += __shfl_xor(zpart, off, 64);
    if (lane == 0) red[w] = zpart;
    __syncthreads();
    if (tid == 0) g_bz[blk] = red[0] + red[1] + red[2] + red[3];
    if (w == 0) {
        #pragma unroll
        for (int off = 32; off > 0; off >>= 1) tpart += __shfl_xor(tpart, off, 64);
        if (lane == 0) g_bt[blk] = tpart;
    }
}

// ---------- k4: final reduce ----------
__global__ __launch_bounds__(TPB)
void k4_final(const float* __restrict__ ws_c, float* __restrict__ out)
{
    __shared__ float rz[4], rt[4];
    const float* g_bz = ws_c + OFF_BZ;
    const float* g_bt = ws_c + OFF_BT;
    const int tid  = threadIdx.x;
    const int lane = tid & 63;
    const int w    = tid >> 6;
    float z = g_bz[tid];
    float t = g_bt[tid];
    #pragma unroll
    for (int off = 32; off > 0; off >>= 1) {
        z += __shfl_xor(z, off, 64);
        t += __shfl_xor(t, off, 64);
    }
    if (lane == 0) { rz[w] = z; rt[w] = t; }
    __syncthreads();
    if (tid == 0) {
        const float sz = rz[0] + rz[1] + rz[2] + rz[3];
        const float st = rt[0] + rt[1] + rt[2] + rt[3];
        const float zl = sz / (100.0f * NS);
        const float tl = st / NS;
        out[0] = zl + tl;
        out[1] = zl;
        out[2] = tl;
    }
}

extern "C" void kernel_launch(void* const* d_in, const int* in_sizes, int n_in,
                              void* d_out, int out_size, void* d_ws, size_t ws_size,
                              hipStream_t stream)
{
    const float* z_seq = (const float*)d_in[0];
    const float* a_seq = (const float*)d_in[1];
    const float* term  = (const float*)d_in[2];
    const float* W1 = (const float*)d_in[3];  const float* b1 = (const float*)d_in[4];
    const float* W2 = (const float*)d_in[5];  const float* b2 = (const float*)d_in[6];
    const float* W3 = (const float*)d_in[7];  const float* b3 = (const float*)d_in[8];
    const float* W4 = (const float*)d_in[9];  const float* b4 = (const float*)d_in[10];
    const float* W5 = (const float*)d_in[11]; const float* b5 = (const float*)d_in[12];
    const float* Wz = (const float*)d_in[13]; const float* bz = (const float*)d_in[14];
    const float* Wt = (const float*)d_in[15]; const float* bt = (const float*)d_in[16];
    float* out = (float*)d_out;
    float* ws  = (float*)d_ws;

    k0_ztrans<<<512, TPB, 0, stream>>>(z_seq, ws + OFF_ZT);
    k0_prep<<<395, TPB, 0, stream>>>(a_seq, W1, W2, W3, W4, W5, Wz, ws);
    k1_encode<<<NBLK, TPB, 0, stream>>>(ws, ws, b1, b2, b3, b4);
    k2_scan<<<1, TPB, 0, stream>>>(ws, ws);
    k3_predict<<<NBLK, TPB, 0, stream>>>(ws, ws, term, b5, bz, Wt, bt);
    k4_final<<<1, TPB, 0, stream>>>(ws, out);
}

// Round 3
// 101.948 us; speedup vs baseline: 1.9172x; 1.4328x over previous
//
#include <hip/hip_runtime.h>
#include <math.h>

#define NS   16383      // T-1 steps
#define NSP  16384      // padded stride for [dim][t] arrays
#define LPB  64         // timesteps per block (= lanes of a wave)
#define NBLK 256        // NS / LPB (ceil)
#define STR  65         // LDS row stride in floats

// ---- ws layout (floats) ----
#define OFF_ZT     0                         // 100*NSP
#define OFF_AT     (OFF_ZT + 100*NSP)        // 2*NSP
#define OFF_INTERT (OFF_AT + 2*NSP)          // 100*NSP
#define OFF_DELTAT (OFF_INTERT + 100*NSP)    // 50*NSP
#define OFF_W1T    (OFF_DELTAT + 50*NSP)     // 102*128
#define OFF_W2T    (OFF_W1T + 102*128)       // 100*128
#define OFF_W3T    (OFF_W2T + 100*128)       // 100*128
#define OFF_W4T    (OFF_W3T + 100*128)       // 100*64
#define OFF_W5T    (OFF_W4T + 100*64)        // 150*128
#define OFF_WZT    (OFF_W5T + 150*128)       // 100*128
#define OFF_CSUM   (OFF_WZT + 100*128)       // 50*NBLK
#define OFF_BZ     (OFF_CSUM + 50*NBLK)      // NBLK
#define OFF_BT     (OFF_BZ + NBLK)           // NBLK

__device__ __forceinline__ float lrelu(float x) { return x >= 0.f ? x : 0.01f * x; }

// dense: 16 neuron slots per wave (8 waves), weights [K][8][16] as float4 (4/wave/k)
#define DENSE16(INLDS, KDIM, WT4, BIAS, acc)                                \
    {                                                                       \
        _Pragma("unroll")                                                   \
        for (int j = 0; j < 16; ++j) {                                      \
            const int n = n0 + j;                                           \
            acc[j] = (n < 100) ? BIAS[n] : 0.f;                             \
        }                                                                   \
        _Pragma("unroll 4")                                                 \
        for (int k = 0; k < (KDIM); ++k) {                                  \
            const float r = INLDS[k * STR + lane];                          \
            const float4* Wk = (WT4) + k * 32 + w * 4;                      \
            _Pragma("unroll")                                               \
            for (int q = 0; q < 4; ++q) {                                   \
                const float4 wv = Wk[q];                                    \
                acc[4*q+0] = fmaf(r, wv.x, acc[4*q+0]);                     \
                acc[4*q+1] = fmaf(r, wv.y, acc[4*q+1]);                     \
                acc[4*q+2] = fmaf(r, wv.z, acc[4*q+2]);                     \
                acc[4*q+3] = fmaf(r, wv.w, acc[4*q+3]);                     \
            }                                                               \
        }                                                                   \
    }

// ---------- k0: fused z-transpose + weight prep ----------
__global__ __launch_bounds__(256)
void k0_prep(const float* __restrict__ z_seq, const float* __restrict__ a_seq,
             const float* __restrict__ W1, const float* __restrict__ W2,
             const float* __restrict__ W3, const float* __restrict__ W4,
             const float* __restrict__ W5, const float* __restrict__ Wz,
             float* __restrict__ ws)
{
    __shared__ float tile[50 * 65];
    const int bid = blockIdx.x;
    const int tid = threadIdx.x;

    if (bid < 512) {   // z transpose: [16384][100] -> zT [100][16384]
        const int tt = bid >> 1;
        const int cc = (bid & 1) * 50;
        for (int idx = tid; idx < 64 * 50; idx += 256) {
            const int l = idx / 50, j = idx - l * 50;
            tile[j * 65 + l] = z_seq[(tt * 64 + l) * 100 + cc + j];
        }
        __syncthreads();
        float* zT = ws + OFF_ZT;
        for (int idx = tid; idx < 50 * 64; idx += 256) {
            const int n = idx >> 6, l = idx & 63;
            zT[(cc + n) * NSP + tt * 64 + l] = tile[n * 65 + l];
        }
        return;
    }

    int idx = (bid - 512) * 256 + tid;
    if (idx < 102 * 128) {                       // W1T [102][128]
        const int k = idx >> 7, s = idx & 127;
        ws[OFF_W1T + idx] = (s < 100) ? W1[s * 102 + k] : 0.f;
        return;
    }
    idx -= 102 * 128;
    if (idx < 100 * 128) {                       // W2T
        const int k = idx >> 7, s = idx & 127;
        ws[OFF_W2T + idx] = (s < 100) ? W2[s * 100 + k] : 0.f;
        return;
    }
    idx -= 100 * 128;
    if (idx < 100 * 128) {                       // W3T
        const int k = idx >> 7, s = idx & 127;
        ws[OFF_W3T + idx] = (s < 100) ? W3[s * 100 + k] : 0.f;
        return;
    }
    idx -= 100 * 128;
    if (idx < 100 * 64) {                        // W4T [100][64]
        const int k = idx >> 6, s = idx & 63;
        ws[OFF_W4T + idx] = (s < 50) ? W4[s * 100 + k] : 0.f;
        return;
    }
    idx -= 100 * 64;
    if (idx < 150 * 128) {                       // W5T [150][128]
        const int k = idx >> 7, s = idx & 127;
        ws[OFF_W5T + idx] = (s < 100) ? W5[s * 150 + k] : 0.f;
        return;
    }
    idx -= 150 * 128;
    if (idx < 100 * 128) {                       // WZT
        const int k = idx >> 7, s = idx & 127;
        ws[OFF_WZT + idx] = (s < 100) ? Wz[s * 100 + k] : 0.f;
        return;
    }
    idx -= 100 * 128;
    if (idx < 2 * NSP) {                         // aT [2][NSP]
        const int j = idx >> 14, t = idx & (NSP - 1);
        ws[OFF_AT + idx] = (t < NS) ? a_seq[t * 2 + j] : 0.f;
        return;
    }
}

// ---------- k1: 4-layer encoder, 8 waves ----------
__global__ __launch_bounds__(512)
void k1_encode(const float* __restrict__ ws_c, float* __restrict__ ws_m,
               const float* __restrict__ b1, const float* __restrict__ b2,
               const float* __restrict__ b3, const float* __restrict__ b4)
{
    __shared__ float A[102 * STR];

    const int tid  = threadIdx.x;
    const int lane = tid & 63;
    const int w    = __builtin_amdgcn_readfirstlane(tid >> 6);   // 0..7
    const int n0   = w * 16;
    const int blk  = blockIdx.x;
    const int t0   = blk * LPB;
    const bool vl  = (t0 + lane) < NS;

    const float*  zT   = ws_c + OFF_ZT;
    const float*  aT   = ws_c + OFF_AT;
    const float4* w1t4 = (const float4*)(ws_c + OFF_W1T);
    const float4* w2t4 = (const float4*)(ws_c + OFF_W2T);
    const float4* w3t4 = (const float4*)(ws_c + OFF_W3T);
    const float4* w4t4 = (const float4*)(ws_c + OFF_W4T);
    float* interT = ws_m + OFF_INTERT;
    float* deltaT = ws_m + OFF_DELTAT;
    float* csum   = ws_m + OFF_CSUM;

    // stage az: rows 0..1 = a, rows 2..101 = z
    for (int idx = tid; idx < 102 * 64; idx += 512) {
        const int rr = idx >> 6, l = idx & 63;
        A[rr * STR + l] = (rr < 2) ? aT[rr * NSP + t0 + l] : zT[(rr - 2) * NSP + t0 + l];
    }
    __syncthreads();

    float acc[16];
    // L1: az(102) -> v1
    DENSE16(A, 102, w1t4, b1, acc);
    __syncthreads();
    #pragma unroll
    for (int j = 0; j < 16; ++j) {
        const int n = n0 + j;
        if (n < 100) A[n * STR + lane] = lrelu(acc[j]);
    }
    __syncthreads();

    // L2: v1 -> inter
    DENSE16(A, 100, w2t4, b2, acc);
    __syncthreads();
    #pragma unroll
    for (int j = 0; j < 16; ++j) {
        const int n = n0 + j;
        if (n < 100) {
            const float v = lrelu(acc[j]);
            A[n * STR + lane] = v;
            if (vl) interT[n * NSP + t0 + lane] = v;
        }
    }
    __syncthreads();

    // L3: inter -> u
    DENSE16(A, 100, w3t4, b3, acc);
    __syncthreads();
    #pragma unroll
    for (int j = 0; j < 16; ++j) {
        const int n = n0 + j;
        if (n < 100) A[n * STR + lane] = lrelu(acc[j]);
    }
    __syncthreads();

    // L4: delta = W4 @ u + b4, 8 slots/wave ([K][8][8])
    {
        float a4[8];
        #pragma unroll
        for (int j = 0; j < 8; ++j) {
            const int n = w * 8 + j;
            a4[j] = (n < 50) ? b4[n] : 0.f;
        }
        #pragma unroll 4
        for (int k = 0; k < 100; ++k) {
            const float r = A[k * STR + lane];
            const float4* Wk = w4t4 + k * 16 + w * 2;
            #pragma unroll
            for (int q = 0; q < 2; ++q) {
                const float4 wv = Wk[q];
                a4[4*q+0] = fmaf(r, wv.x, a4[4*q+0]);
                a4[4*q+1] = fmaf(r, wv.y, a4[4*q+1]);
                a4[4*q+2] = fmaf(r, wv.z, a4[4*q+2]);
                a4[4*q+3] = fmaf(r, wv.w, a4[4*q+3]);
            }
        }
        #pragma unroll
        for (int j = 0; j < 8; ++j) {
            const int n = w * 8 + j;
            if (n < 50) {
                const float d = vl ? a4[j] : 0.f;
                deltaT[n * NSP + t0 + lane] = d;
                float s = d;
                #pragma unroll
                for (int off = 32; off > 0; off >>= 1) s += __shfl_xor(s, off, 64);
                if (lane == 0) csum[n * NBLK + blk] = s;
            }
        }
    }
}

// ---------- k3: chunk-offset + h-scan + predict + losses (8 waves) ----------
__global__ __launch_bounds__(512)
void k3_predict(const float* __restrict__ ws_c, float* __restrict__ ws_m,
                const float* __restrict__ term_seq,
                const float* __restrict__ b5, const float* __restrict__ bz,
                const float* __restrict__ Wt, const float* __restrict__ bt)
{
    __shared__ float X[100 * STR];   // inter -> i5
    __shared__ float H[50 * STR];    // delta -> h
    __shared__ float coff_s[50];
    __shared__ float red[8];

    const int tid  = threadIdx.x;
    const int lane = tid & 63;
    const int w    = __builtin_amdgcn_readfirstlane(tid >> 6);
    const int n0   = w * 16;
    const int blk  = blockIdx.x;
    const int t0   = blk * LPB;
    const bool vl  = (t0 + lane) < NS;

    const float*  zT     = ws_c + OFF_ZT;
    const float*  interT = ws_c + OFF_INTERT;
    const float*  deltaT = ws_c + OFF_DELTAT;
    const float*  csum   = ws_c + OFF_CSUM;
    const float4* w5t4   = (const float4*)(ws_c + OFF_W5T);
    const float4* wzt4   = (const float4*)(ws_c + OFF_WZT);
    float* g_bz = ws_m + OFF_BZ;
    float* g_bt = ws_m + OFF_BT;

    for (int idx = tid; idx < 100 * 64; idx += 512) {
        const int n = idx >> 6, l = idx & 63;
        X[n * STR + l] = (t0 + l < NS) ? interT[n * NSP + t0 + l] : 0.f;
    }
    for (int idx = tid; idx < 50 * 64; idx += 512) {
        const int n = idx >> 6, l = idx & 63;
        H[n * STR + l] = deltaT[n * NSP + t0 + l];
    }

    // chunk offsets: sum csum[n][0..blk) cooperatively (lanes split chunks)
    for (int n = w; n < 50; n += 8) {
        float s = 0.f;
        #pragma unroll
        for (int i = 0; i < 4; ++i) {
            const int c = lane + 64 * i;
            if (c < blk) s += csum[n * NBLK + c];
        }
        #pragma unroll
        for (int off = 32; off > 0; off >>= 1) s += __shfl_xor(s, off, 64);
        if (lane == 0) coff_s[n] = s;
    }
    __syncthreads();

    // inclusive scan over 64 lanes per h-dim + chunk offset
    for (int n = w; n < 50; n += 8) {
        float v = H[n * STR + lane];
        #pragma unroll
        for (int off = 1; off < 64; off <<= 1) {
            const float u = __shfl_up(v, off, 64);
            if (lane >= off) v += u;
        }
        H[n * STR + lane] = v + coff_s[n];
    }
    __syncthreads();

    // L5: i5 = lrelu(W5 @ [h(50); inter(100)] + b5)
    float acc[16];
    #pragma unroll
    for (int j = 0; j < 16; ++j) {
        const int n = n0 + j;
        acc[j] = (n < 100) ? b5[n] : 0.f;
    }
    #pragma unroll 4
    for (int k = 0; k < 50; ++k) {
        const float r = H[k * STR + lane];
        const float4* Wk = w5t4 + k * 32 + w * 4;
        #pragma unroll
        for (int q = 0; q < 4; ++q) {
            const float4 wv = Wk[q];
            acc[4*q+0] = fmaf(r, wv.x, acc[4*q+0]);
            acc[4*q+1] = fmaf(r, wv.y, acc[4*q+1]);
            acc[4*q+2] = fmaf(r, wv.z, acc[4*q+2]);
            acc[4*q+3] = fmaf(r, wv.w, acc[4*q+3]);
        }
    }
    #pragma unroll 4
    for (int k = 0; k < 100; ++k) {
        const float r = X[k * STR + lane];
        const float4* Wk = w5t4 + (50 + k) * 32 + w * 4;
        #pragma unroll
        for (int q = 0; q < 4; ++q) {
            const float4 wv = Wk[q];
            acc[4*q+0] = fmaf(r, wv.x, acc[4*q+0]);
            acc[4*q+1] = fmaf(r, wv.y, acc[4*q+1]);
            acc[4*q+2] = fmaf(r, wv.z, acc[4*q+2]);
            acc[4*q+3] = fmaf(r, wv.w, acc[4*q+3]);
        }
    }
    __syncthreads();
    #pragma unroll
    for (int j = 0; j < 16; ++j) {
        const int n = n0 + j;
        if (n < 100) X[n * STR + lane] = lrelu(acc[j]);
    }
    __syncthreads();

    // prefetch z_next (hidden under Wz dense loop)
    float zn[16];
    {
        const int t1 = min(t0 + lane + 1, NS);
        #pragma unroll
        for (int j = 0; j < 16; ++j) {
            const int n = n0 + j;
            zn[j] = (n < 100) ? zT[n * NSP + t1] : 0.f;
        }
    }

    // z_pred = Wz @ i5 + bz; squared error
    float zpart = 0.f;
    {
        float a2[16];
        #pragma unroll
        for (int j = 0; j < 16; ++j) {
            const int n = n0 + j;
            a2[j] = (n < 100) ? bz[n] : 0.f;
        }
        #pragma unroll 4
        for (int k = 0; k < 100; ++k) {
            const float r = X[k * STR + lane];
            const float4* Wk = wzt4 + k * 32 + w * 4;
            #pragma unroll
            for (int q = 0; q < 4; ++q) {
                const float4 wv = Wk[q];
                a2[4*q+0] = fmaf(r, wv.x, a2[4*q+0]);
                a2[4*q+1] = fmaf(r, wv.y, a2[4*q+1]);
                a2[4*q+2] = fmaf(r, wv.z, a2[4*q+2]);
                a2[4*q+3] = fmaf(r, wv.w, a2[4*q+3]);
            }
        }
        #pragma unroll
        for (int j = 0; j < 16; ++j) {
            const int n = n0 + j;
            if (n < 100) {
                const float d = zn[j] - a2[j];
                zpart += d * d;
            }
        }
        if (!vl) zpart = 0.f;
    }

    // t_logit + BCE (wave 0)
    float tpart = 0.f;
    if (w == 0) {
        float a = bt[0];
        #pragma unroll 4
        for (int k = 0; k < 100; ++k) a = fmaf(X[k * STR + lane], Wt[k], a);
        if (vl) {
            const float y = term_seq[t0 + lane + 1];
            tpart = fmaxf(a, 0.f) - a * y + log1pf(expf(-fabsf(a)));
        }
    }

    #pragma unroll
    for (int off = 32; off > 0; off >>= 1) zpart += __shfl_xor(zpart, off, 64);
    if (lane == 0) red[w] = zpart;
    __syncthreads();
    if (tid == 0) {
        float s = 0.f;
        #pragma unroll
        for (int i = 0; i < 8; ++i) s += red[i];
        g_bz[blk] = s;
    }
    if (w == 0) {
        #pragma unroll
        for (int off = 32; off > 0; off >>= 1) tpart += __shfl_xor(tpart, off, 64);
        if (lane == 0) g_bt[blk] = tpart;
    }
}

// ---------- k4: final reduce ----------
__global__ __launch_bounds__(256)
void k4_final(const float* __restrict__ ws_c, float* __restrict__ out)
{
    __shared__ float rz[4], rt[4];
    const float* g_bz = ws_c + OFF_BZ;
    const float* g_bt = ws_c + OFF_BT;
    const int tid  = threadIdx.x;
    const int lane = tid & 63;
    const int w    = tid >> 6;
    float z = g_bz[tid];
    float t = g_bt[tid];
    #pragma unroll
    for (int off = 32; off > 0; off >>= 1) {
        z += __shfl_xor(z, off, 64);
        t += __shfl_xor(t, off, 64);
    }
    if (lane == 0) { rz[w] = z; rt[w] = t; }
    __syncthreads();
    if (tid == 0) {
        const float sz = rz[0] + rz[1] + rz[2] + rz[3];
        const float st = rt[0] + rt[1] + rt[2] + rt[3];
        const float zl = sz / (100.0f * NS);
        const float tl = st / NS;
        out[0] = zl + tl;
        out[1] = zl;
        out[2] = tl;
    }
}

extern "C" void kernel_launch(void* const* d_in, const int* in_sizes, int n_in,
                              void* d_out, int out_size, void* d_ws, size_t ws_size,
                              hipStream_t stream)
{
    const float* z_seq = (const float*)d_in[0];
    const float* a_seq = (const float*)d_in[1];
    const float* term  = (const float*)d_in[2];
    const float* W1 = (const float*)d_in[3];  const float* b1 = (const float*)d_in[4];
    const float* W2 = (const float*)d_in[5];  const float* b2 = (const float*)d_in[6];
    const float* W3 = (const float*)d_in[7];  const float* b3 = (const float*)d_in[8];
    const float* W4 = (const float*)d_in[9];  const float* b4 = (const float*)d_in[10];
    const float* W5 = (const float*)d_in[11]; const float* b5 = (const float*)d_in[12];
    const float* Wz = (const float*)d_in[13]; const float* bz = (const float*)d_in[14];
    const float* Wt = (const float*)d_in[15]; const float* bt = (const float*)d_in[16];
    float* out = (float*)d_out;
    float* ws  = (float*)d_ws;

    k0_prep<<<941, 256, 0, stream>>>(z_seq, a_seq, W1, W2, W3, W4, W5, Wz, ws);
    k1_encode<<<NBLK, 512, 0, stream>>>(ws, ws, b1, b2, b3, b4);
    k3_predict<<<NBLK, 512, 0, stream>>>(ws, ws, term, b5, bz, Wt, bt);
    k4_final<<<1, 256, 0, stream>>>(ws, out);
}